// Round 1
// baseline (184.912 us; speedup 1.0000x reference)
//
#include <hip/hip_runtime.h>
#include <stdint.h>

#define KK 1000
#define NN 1000
#define MM 900000
#define FF 7
#define SENTINEL -9999.0f

// Compile-time unroller: every loop index reaches the body as a constant
// expression after inlining, so h1/h2 decompose into named scalars (SROA).
// Plain `#pragma unroll` left the arrays runtime-indexed at SROA time ->
// scratch spill (R1/R2: VGPR=32..40, +20MB HBM writes, VALUBusy 62%).
template <int N, typename F>
__device__ __forceinline__ void unroll_loop(F&& f) {
    if constexpr (N > 0) {
        unroll_loop<N - 1>(static_cast<F&&>(f));
        f(N - 1);
    }
}

// ---------------- init: zero packed grid + sentinel the col-max outputs -----
__global__ __launch_bounds__(256) void init_grid(ulonglong2* __restrict__ g, int n2,
                                                 float* __restrict__ outcol) {
    int i = blockIdx.x * 256 + threadIdx.x;
    if (i < n2) g[i] = make_ulonglong2(0ULL, 0ULL);
    if (i < NN) outcol[i] = SENTINEL;
}

// ---------------- MLP + last-write-wins scatter, P=2 points/thread ----------
// Each uniform weight (SGPR) now feeds TWO fmas: halves the s_load->s_waitcnt
// treadmill that stall-bound the P=1 version (true VALU issue was ~29% of the
// kernel; weight refetch latency was the gap). Two independent chains also
// double per-wave ILP. Peak live set ~= h2[2][36] + h1[2][18] + temps
// ~= 120 VGPR -> launch_bounds(256,3) caps at 168: no spill, 3 waves/SIMD.
__global__ __launch_bounds__(256, 3) void mlp_scatter(
    const float* __restrict__ in,    // [F][M]
    const int*   __restrict__ idx,   // [2][M]
    const float* __restrict__ w1, const float* __restrict__ b1,   // 18x7, 18
    const float* __restrict__ w2, const float* __restrict__ b2,   // 36x18, 36
    const float* __restrict__ w3, const float* __restrict__ b3,   // 36x36, 36
    const float* __restrict__ w4, const float* __restrict__ b4,   // 1x36, 1
    unsigned long long* __restrict__ grid)                        // K*N packed
{
    int t = blockIdx.x * 256 + threadIdx.x;
    int m0 = t * 2;                       // adjacent pair -> float2 loads stay
    if (m0 >= MM) return;                 // coalesced (512B per wave per instr)

    float xa[FF], xb[FF];
    unroll_loop<FF>([&](int f) {
        float2 v = *reinterpret_cast<const float2*>(in + (size_t)f * MM + m0);
        xa[f] = v.x; xb[f] = v.y;
    });

    float h1a[18], h1b[18];
    unroll_loop<18>([&](int o) {
        float a = b1[o], b = a;
        unroll_loop<FF>([&](int i) {
            float w_ = w1[o * FF + i];
            a = fmaf(w_, xa[i], a); b = fmaf(w_, xb[i], b);
        });
        h1a[o] = fmaxf(a, 0.0f); h1b[o] = fmaxf(b, 0.0f);
    });

    float h2a[36], h2b[36];
    unroll_loop<36>([&](int o) {
        float a = b2[o], b = a;
        unroll_loop<18>([&](int i) {
            float w_ = w2[o * 18 + i];
            a = fmaf(w_, h1a[i], a); b = fmaf(w_, h1b[i], b);
        });
        h2a[o] = fmaxf(a, 0.0f); h2b[o] = fmaxf(b, 0.0f);
    });

    // Layer 3 fused with layer 4: h3 never materializes.
    float va = b4[0], vb = va;
    unroll_loop<36>([&](int o) {
        float a = b3[o], b = a;
        unroll_loop<36>([&](int i) {
            float w_ = w3[o * 36 + i];
            a = fmaf(w_, h2a[i], a); b = fmaf(w_, h2b[i], b);
        });
        float w4o = w4[o];
        va = fmaf(w4o, fmaxf(a, 0.0f), va);
        vb = fmaf(w4o, fmaxf(b, 0.0f), vb);
    });

    int2 rr = *reinterpret_cast<const int2*>(idx + m0);        // rows r0,r1
    int2 cc = *reinterpret_cast<const int2*>(idx + MM + m0);   // cols c0,c1
    // high word = m+1 (unique, later m wins => numpy last-write-wins),
    // low word = value bits (payload only, never decides the compare)
    unsigned long long pa =
        ((unsigned long long)(unsigned)(m0 + 1) << 32) | (unsigned)__float_as_uint(va);
    unsigned long long pb =
        ((unsigned long long)(unsigned)(m0 + 2) << 32) | (unsigned)__float_as_uint(vb);
    atomicMax(&grid[rr.x * NN + cc.x], pa);
    atomicMax(&grid[rr.y * NN + cc.y], pb);
}

// ---------------- fused epilogue: rows by block, cols by atomic -------------
#define CCHUNKS 25
#define CROWS   (KK / CCHUNKS)   // 40

__global__ __launch_bounds__(256) void maxes(const unsigned long long* __restrict__ g,
                                             float* __restrict__ out) {
    int b = blockIdx.x;
    if (b < KK) {
        // --- row max: one block per row ---
        int r = b;
        float mx = SENTINEL;
        for (int c = threadIdx.x; c < NN; c += 256) {
            unsigned long long p = g[(size_t)r * NN + c];
            if (p) mx = fmaxf(mx, __uint_as_float((unsigned)p));
        }
        __shared__ float red[256];
        red[threadIdx.x] = mx;
        __syncthreads();
        for (int s = 128; s > 0; s >>= 1) {
            if (threadIdx.x < s)
                red[threadIdx.x] = fmaxf(red[threadIdx.x], red[threadIdx.x + s]);
            __syncthreads();
        }
        if (threadIdx.x == 0) out[r] = red[0];
    } else {
        // --- col partial max over a 40-row chunk, finished via float atomicMax
        // (out[KK..KK+NN) pre-set to SENTINEL by init_grid; all values finite,
        // so IEEE fmax-atomic semantics are safe) ---
        int cb = b - KK;                       // 0..99
        int n  = (cb & 3) * 256 + (int)threadIdx.x;
        if (n < NN) {
            int k0 = (cb >> 2) * CROWS;
            float mx = SENTINEL;
            for (int k = k0; k < k0 + CROWS; ++k) {
                unsigned long long p = g[(size_t)k * NN + n];
                if (p) mx = fmaxf(mx, __uint_as_float((unsigned)p));
            }
            atomicMax(out + KK + n, mx);
        }
    }
}

extern "C" void kernel_launch(void* const* d_in, const int* in_sizes, int n_in,
                              void* d_out, int out_size, void* d_ws, size_t ws_size,
                              hipStream_t stream) {
    const float* in  = (const float*)d_in[0];
    // d_in[1] = T_out (zeros) — unused
    const int*   idx = (const int*)d_in[2];
    const float* w1  = (const float*)d_in[3];
    const float* b1  = (const float*)d_in[4];
    const float* w2  = (const float*)d_in[5];
    const float* b2  = (const float*)d_in[6];
    const float* w3  = (const float*)d_in[7];
    const float* b3  = (const float*)d_in[8];
    const float* w4  = (const float*)d_in[9];
    const float* b4  = (const float*)d_in[10];

    unsigned long long* grid = (unsigned long long*)d_ws;   // 8 MB
    float* out = (float*)d_out;

    const int n2 = (KK * NN) / 2;  // ulonglong2 elements
    init_grid<<<(n2 + 255) / 256, 256, 0, stream>>>((ulonglong2*)grid, n2, out + KK);

    mlp_scatter<<<(MM / 2 + 255) / 256, 256, 0, stream>>>(
        in, idx, w1, b1, w2, b2, w3, b3, w4, b4, grid);

    maxes<<<KK + 100, 256, 0, stream>>>(grid, out);
}

// Round 3
// 156.122 us; speedup vs baseline: 1.1844x; 1.1844x over previous
//
#include <hip/hip_runtime.h>
#include <stdint.h>

#define KK 1000
#define NN 1000
#define MM 900000
#define FF 7
#define SENTINEL -9999.0f

typedef _Float16 h2v __attribute__((ext_vector_type(2)));
typedef __fp16  h2f __attribute__((ext_vector_type(2)));   // builtin return type

// Compile-time unroller: every loop index reaches the body as a constant
// expression after inlining, so activation arrays decompose into named
// scalars (SROA). Plain `#pragma unroll` left them runtime-indexed at SROA
// time -> scratch spill.
template <int N, typename F>
__device__ __forceinline__ void unroll_loop(F&& f) {
    if constexpr (N > 0) {
        unroll_loop<N - 1>(static_cast<F&&>(f));
        f(N - 1);
    }
}

// v_dot2_f32_f16: 2 f16 MACs + f32 accumulate in ONE VALU instruction.
// Halves the instruction count of layers 2/3 (63% of all FLOPs) and halves
// the live activation registers (half2 packs). f32 accumulation keeps the
// error at input-rounding level (~1e-3 abs on outputs of magnitude ~0.3).
#if __has_builtin(__builtin_amdgcn_fdot2)
__device__ __forceinline__ float dot2(h2v a, h2v b, float c) {
    return __builtin_amdgcn_fdot2(__builtin_bit_cast(h2f, a),
                                  __builtin_bit_cast(h2f, b), c, false);
}
#else
__device__ __forceinline__ float dot2(h2v a, h2v b, float c) {
    return fmaf((float)a.x, (float)b.x, fmaf((float)a.y, (float)b.y, c));
}
#endif

__device__ __forceinline__ h2v pkrtz(float a, float b) {
#if __has_builtin(__builtin_amdgcn_cvt_pkrtz)
    // builtin returns __fp16-vec2; identical bits to _Float16-vec2
    return __builtin_bit_cast(h2v, __builtin_amdgcn_cvt_pkrtz(a, b));
#else
    return h2v{(_Float16)a, (_Float16)b};
#endif
}

// ---------------- pack f32 weights -> f16 pairs (one tiny block) ------------
// RTNE casts; runs once before mlp_scatter on the same stream.
__global__ __launch_bounds__(256) void pack_weights(
    const float* __restrict__ w2, const float* __restrict__ w3,
    h2v* __restrict__ w2h, h2v* __restrict__ w3h) {
    int t = threadIdx.x;
    for (int p = t; p < 36 * 9; p += 256) {           // w2: 36x18 -> [36][9]
        int o = p / 9, ip = p - o * 9;
        w2h[p] = h2v{(_Float16)w2[o * 18 + 2 * ip], (_Float16)w2[o * 18 + 2 * ip + 1]};
    }
    for (int p = t; p < 36 * 18; p += 256) {          // w3: 36x36 -> [36][18]
        int o = p / 18, ip = p - o * 18;
        w3h[p] = h2v{(_Float16)w3[o * 36 + 2 * ip], (_Float16)w3[o * 36 + 2 * ip + 1]};
    }
}

// ---------------- init: zero the packed grid (ws is poisoned 0xAA) ----------
__global__ __launch_bounds__(256) void init_grid(ulonglong2* __restrict__ g, int n2) {
    int i = blockIdx.x * 256 + threadIdx.x;
    if (i < n2) g[i] = make_ulonglong2(0ULL, 0ULL);
}

// ---------------- MLP + last-write-wins scatter -----------------------------
// P=1 (R1 showed P=2 is neutral: the binding resource scales with
// instructions/live-regs per point, which P=2 doubled right back).
// f16 dot2 cuts VALU ops/point 2290 -> ~1300 and peak live set to ~30 regs:
// attacks instruction issue, scratch spill, and I$ footprint simultaneously.
__global__ __launch_bounds__(256, 4) void mlp_scatter(
    const float* __restrict__ in,    // [F][M]
    const int*   __restrict__ idx,   // [2][M]
    const float* __restrict__ w1, const float* __restrict__ b1,   // 18x7, 18
    const h2v*   __restrict__ w2h, const float* __restrict__ b2,  // [36][9], 36
    const h2v*   __restrict__ w3h, const float* __restrict__ b3,  // [36][18], 36
    const float* __restrict__ w4, const float* __restrict__ b4,   // 1x36, 1
    unsigned long long* __restrict__ grid)                        // K*N packed
{
    int m = blockIdx.x * 256 + threadIdx.x;
    if (m >= MM) return;

    float x[FF];
    unroll_loop<FF>([&](int f) { x[f] = in[(size_t)f * MM + m]; });

    // Layer 1 in f32 (126 FMAs, cheap), outputs packed immediately so the
    // f32 pair dies each iteration: live = x[7] + h1h[<=9] + 2 accs.
    h2v h1h[9];
    unroll_loop<9>([&](int p) {
        float a = b1[2 * p], b = b1[2 * p + 1];
        unroll_loop<FF>([&](int i) {
            a = fmaf(w1[(2 * p) * FF + i], x[i], a);
            b = fmaf(w1[(2 * p + 1) * FF + i], x[i], b);
        });
        h1h[p] = pkrtz(fmaxf(a, 0.0f), fmaxf(b, 0.0f));
    });

    // Layer 2: 36 outputs computed in even/odd pairs -> packed immediately.
    // Live = h1h[9] + h2h[<=18] + 2 accs (~29 regs peak).
    h2v h2h[18];
    unroll_loop<18>([&](int p) {
        float a = b2[2 * p], b = b2[2 * p + 1];
        unroll_loop<9>([&](int ip) {
            a = dot2(w2h[(2 * p) * 9 + ip], h1h[ip], a);
            b = dot2(w2h[(2 * p + 1) * 9 + ip], h1h[ip], b);
        });
        h2h[p] = pkrtz(fmaxf(a, 0.0f), fmaxf(b, 0.0f));
    });

    // Layer 3 fused with layer 4: h3 never materializes.
    float v = b4[0];
    unroll_loop<36>([&](int o) {
        float a = b3[o];
        unroll_loop<18>([&](int ip) { a = dot2(w3h[o * 18 + ip], h2h[ip], a); });
        v = fmaf(w4[o], fmaxf(a, 0.0f), v);
    });

    int r = idx[m];
    int c = idx[MM + m];
    // high word = m+1 (unique, later m wins => numpy last-write-wins),
    // low word = value bits (payload only, never decides the compare)
    unsigned long long packed =
        ((unsigned long long)(unsigned)(m + 1) << 32) | (unsigned)__float_as_uint(v);
    atomicMax(&grid[r * NN + c], packed);
}

// ---------------- row max: one block per row --------------------------------
__global__ __launch_bounds__(256) void row_max_k(const unsigned long long* __restrict__ g,
                                                 float* __restrict__ out) {
    int r = blockIdx.x;
    float mx = SENTINEL;
    for (int c = threadIdx.x; c < NN; c += 256) {
        unsigned long long p = g[(size_t)r * NN + c];
        if (p) mx = fmaxf(mx, __uint_as_float((unsigned)p));
    }
    __shared__ float red[256];
    red[threadIdx.x] = mx;
    __syncthreads();
    for (int s = 128; s > 0; s >>= 1) {
        if (threadIdx.x < s) red[threadIdx.x] = fmaxf(red[threadIdx.x], red[threadIdx.x + s]);
        __syncthreads();
    }
    if (threadIdx.x == 0) out[r] = red[0];
}

// ---------------- col max: partials over row-chunks, then final -------------
#define CCHUNKS 25
#define CROWS   (KK / CCHUNKS)   // 40

__global__ __launch_bounds__(256) void col_partial(const unsigned long long* __restrict__ g,
                                                   float* __restrict__ part) {
    int n = blockIdx.x * 256 + threadIdx.x;
    if (n >= NN) return;
    int k0 = blockIdx.y * CROWS;
    float mx = SENTINEL;
    for (int k = k0; k < k0 + CROWS; ++k) {
        unsigned long long p = g[(size_t)k * NN + n];
        if (p) mx = fmaxf(mx, __uint_as_float((unsigned)p));
    }
    part[blockIdx.y * NN + n] = mx;
}

__global__ __launch_bounds__(256) void col_final(const float* __restrict__ part,
                                                 float* __restrict__ out) {
    int n = blockIdx.x * 256 + threadIdx.x;
    if (n >= NN) return;
    float mx = SENTINEL;
#pragma unroll
    for (int c = 0; c < CCHUNKS; ++c) mx = fmaxf(mx, part[c * NN + n]);
    out[KK + n] = mx;
}

extern "C" void kernel_launch(void* const* d_in, const int* in_sizes, int n_in,
                              void* d_out, int out_size, void* d_ws, size_t ws_size,
                              hipStream_t stream) {
    const float* in  = (const float*)d_in[0];
    // d_in[1] = T_out (zeros) — unused
    const int*   idx = (const int*)d_in[2];
    const float* w1  = (const float*)d_in[3];
    const float* b1  = (const float*)d_in[4];
    const float* w2  = (const float*)d_in[5];
    const float* b2  = (const float*)d_in[6];
    const float* w3  = (const float*)d_in[7];
    const float* b3  = (const float*)d_in[8];
    const float* w4  = (const float*)d_in[9];
    const float* b4  = (const float*)d_in[10];

    unsigned long long* grid = (unsigned long long*)d_ws;            // 8 MB
    float* part = (float*)((char*)d_ws + (size_t)KK * NN * 8);       // 100 KB
    // packed f16 weights right after part (offsets 16B-aligned; +3.9 KB ws)
    h2v* w2h = (h2v*)((char*)d_ws + (size_t)KK * NN * 8 + 100000);   // 324*4 B
    h2v* w3h = (h2v*)((char*)d_ws + (size_t)KK * NN * 8 + 101296);   // 648*4 B
    float* out  = (float*)d_out;

    pack_weights<<<1, 256, 0, stream>>>(w2, w3, w2h, w3h);

    const int n2 = (KK * NN) / 2;  // ulonglong2 elements
    init_grid<<<(n2 + 255) / 256, 256, 0, stream>>>((ulonglong2*)grid, n2);

    mlp_scatter<<<(MM + 255) / 256, 256, 0, stream>>>(
        in, idx, w1, b1, w2h, b2, w3h, b3, w4, b4, grid);

    row_max_k<<<KK, 256, 0, stream>>>(grid, out);
    col_partial<<<dim3(4, CCHUNKS), 256, 0, stream>>>(grid, part);
    col_final<<<4, 256, 0, stream>>>(part, out);
}